// Round 10
// baseline (301.572 us; speedup 1.0000x reference)
//
#include <hip/hip_runtime.h>
#include <math.h>

#define N_NODES 10000
#define E_EDGES 320000
#define M_TRAIN 100000
#define P_PAIRS 15000
#define TILES2  79            // 128-tile count: ceil(10000/128)
#define NTRI2   3160          // TILES2*(TILES2+1)/2
#define NPAD2   10112         // 79*128 padded rows
#define EXACT_BLOCKS 256
#define RB 782                // real-loss blocks (6250 groups / 8 waves)
#define LB 118                // lc blocks (938 groups / 8 waves)
#define NB 79                 // negs blocks (625 groups / 8 waves)
#define AGG_MAIN 5000
#define AGG_PAD  14           // zero 112 pad rows of xbf (3584 uint2 / 256)

typedef __attribute__((ext_vector_type(8))) short short8;   // 8 bf16 (4 VGPRs)
typedef __attribute__((ext_vector_type(4))) float f32x4;

__device__ __forceinline__ float wred64(float v) {
#pragma unroll
    for (int o = 32; o > 0; o >>= 1) v += __shfl_xor(v, o, 64);
    return v;
}

__device__ __forceinline__ unsigned short f2bf(float f) {   // RNE float->bf16
    unsigned u = __float_as_uint(f);
    u += 0x7fffu + ((u >> 16) & 1u);
    return (unsigned short)(u >> 16);
}
__device__ __forceinline__ float bf2f(unsigned short h) {
    return __uint_as_float((unsigned)h << 16);
}

// ======= prep: x hi/lo bf16 split + W^T hi/lo + edge histograms =============
__global__ __launch_bounds__(256) void k_prep(const float* __restrict__ x0,
                                              const float* __restrict__ x1,
                                              const float* __restrict__ W0,
                                              const float* __restrict__ W1,
                                              const int* __restrict__ d0,
                                              const int* __restrict__ d1,
                                              unsigned short* __restrict__ xh,
                                              unsigned short* __restrict__ xl,
                                              unsigned short* __restrict__ wth,
                                              unsigned short* __restrict__ wtl,
                                              int* __restrict__ hist) {
    int b = blockIdx.x;
    const int t = threadIdx.x;
    if (b < 5056) {                         // ---- x hi/lo split ----
        const int half = b >= 2528;
        if (half) b -= 2528;
        const float* x = half ? x1 : x0;
        unsigned short* ph = xh + (size_t)half * NPAD2 * 256;
        unsigned short* pl = xl + (size_t)half * NPAD2 * 256;
        const int tid = b * 256 + t;        // one float4 per thread
        const int row = tid >> 6;
        uint2 ho = {0, 0}, lo = {0, 0};
        if (row < N_NODES) {
            const float4 v = ((const float4*)x)[tid];
            const unsigned short h0 = f2bf(v.x), h1 = f2bf(v.y);
            const unsigned short h2 = f2bf(v.z), h3 = f2bf(v.w);
            ho.x = (unsigned)h0 | ((unsigned)h1 << 16);
            ho.y = (unsigned)h2 | ((unsigned)h3 << 16);
            lo.x = (unsigned)f2bf(v.x - bf2f(h0)) |
                   ((unsigned)f2bf(v.y - bf2f(h1)) << 16);
            lo.y = (unsigned)f2bf(v.z - bf2f(h2)) |
                   ((unsigned)f2bf(v.w - bf2f(h3)) << 16);
        }
        ((uint2*)ph)[tid] = ho;
        ((uint2*)pl)[tid] = lo;
    } else if (b < 5312) {                  // ---- W^T hi/lo ----
        b -= 5056;
        const int half = b >= 128;
        if (half) b -= 128;
        const float* W = half ? W1 : W0;
        unsigned short* th = wth + half * 32768;
        unsigned short* tl = wtl + half * 32768;
        const int idx = b * 256 + t;        // idx = k*128 + n
        const int k = idx >> 7, n = idx & 127;
        const float v = W[idx];
        const unsigned short h = f2bf(v);
        th[n * 256 + k] = h;
        tl[n * 256 + k] = f2bf(v - bf2f(h));
    } else {                                // ---- histogram ----
        b -= 5312;
        const int* dst;
        int* h;
        if (b < 1250) { dst = d0; h = hist; }
        else { b -= 1250; dst = d1; h = hist + 10240; }
        atomicAdd(&h[dst[b * 256 + t]], 1);
    }
}

// ======= MFMA GEMM (bf16x2-split), 64x64 tiles, reg-staged dbuf + scan ======
__global__ __launch_bounds__(256) void k_gemmscan(const unsigned short* __restrict__ xh,
                                                  const unsigned short* __restrict__ xl,
                                                  const unsigned short* __restrict__ wth,
                                                  const unsigned short* __restrict__ wtl,
                                                  const float* __restrict__ b0,
                                                  const float* __restrict__ b1,
                                                  float* __restrict__ sup0,
                                                  float* __restrict__ sup1,
                                                  const int* __restrict__ hist_,
                                                  int* __restrict__ off_,
                                                  int* __restrict__ cur_) {
    __shared__ unsigned short Ah[2][64 * 32], Al[2][64 * 32];
    __shared__ unsigned short Bh[2][64 * 32], Bl[2][64 * 32];
    __shared__ int ss[256];
    const int b = blockIdx.x;
    const int t = threadIdx.x;
    if (b >= 632) {                         // ---- scan ----
        const int h = b - 632;
        const int* hist = hist_ + h * 10240;
        int* off = off_ + h * 10240;
        int* cur = cur_ + h * 10240;
        int loc[40];
        int sum = 0;
        const int base = t * 40;
#pragma unroll
        for (int i = 0; i < 40; i++) { loc[i] = hist[base + i]; sum += loc[i]; }
        ss[t] = sum;
        __syncthreads();
        for (int o = 1; o < 256; o <<= 1) {
            int v = (t >= o) ? ss[t - o] : 0;
            __syncthreads();
            ss[t] += v;
            __syncthreads();
        }
        int run = ss[t] - sum;
#pragma unroll
        for (int i = 0; i < 40; i++) {
            off[base + i] = run;
            cur[base + i] = run;
            run += loc[i];
        }
        return;
    }
    const int half = b >= 316;
    const int r_ = half ? b - 316 : b;
    const int rt = r_ >> 1, ct = r_ & 1;
    const unsigned short* xhp = xh + (size_t)half * NPAD2 * 256;
    const unsigned short* xlp = xl + (size_t)half * NPAD2 * 256;
    const unsigned short* bhp = wth + half * 32768;
    const unsigned short* blp = wtl + half * 32768;
    const float* bias = half ? b1 : b0;
    float* sup = half ? sup1 : sup0;
    const int i0 = rt * 64, j0 = ct * 64;
    const int wave = t >> 6, lane = t & 63;
    const int wi = wave >> 1, wj = wave & 1;
    const int m = lane & 15, kq = lane >> 4;
    const int srow = lane >> 2, scol = lane & 3;
    const int skey = (srow >> 1) & 3;       // staging XOR key
    const int rkey = (m >> 1) & 3;          // read XOR key

    // staging pointers (register path) + LDS deposit offset (contiguous 1KB/wave)
    const unsigned short* pAh = xhp + (size_t)(i0 + wave * 16 + srow) * 256 + (scol ^ skey) * 8;
    const unsigned short* pAl = xlp + (size_t)(i0 + wave * 16 + srow) * 256 + (scol ^ skey) * 8;
    const unsigned short* pBh = bhp + (size_t)(j0 + wave * 16 + srow) * 256 + (scol ^ skey) * 8;
    const unsigned short* pBl = blp + (size_t)(j0 + wave * 16 + srow) * 256 + (scol ^ skey) * 8;
    const int woff = wave * 512 + srow * 32 + scol * 8;

    f32x4 acc[2][2];
#pragma unroll
    for (int r = 0; r < 2; r++)
#pragma unroll
        for (int c = 0; c < 2; c++) acc[r][c] = (f32x4){0.f, 0.f, 0.f, 0.f};

    {   // stage kt=0 via regs
        uint4 a0 = *(const uint4*)pAh;
        uint4 a1 = *(const uint4*)pAl;
        uint4 w0 = *(const uint4*)pBh;
        uint4 w1 = *(const uint4*)pBl;
        *(uint4*)&Ah[0][woff] = a0;
        *(uint4*)&Al[0][woff] = a1;
        *(uint4*)&Bh[0][woff] = w0;
        *(uint4*)&Bl[0][woff] = w1;
    }
    __syncthreads();

#pragma unroll
    for (int kt = 0; kt < 8; kt++) {
        const int buf = kt & 1;
        uint4 a0n, a1n, w0n, w1n;
        if (kt < 7) {                       // prefetch kt+1 into regs
            a0n = *(const uint4*)(pAh + (kt + 1) * 32);
            a1n = *(const uint4*)(pAl + (kt + 1) * 32);
            w0n = *(const uint4*)(pBh + (kt + 1) * 32);
            w1n = *(const uint4*)(pBl + (kt + 1) * 32);
        }
        short8 ah[2], al[2], bh[2], bl[2];
#pragma unroll
        for (int mt = 0; mt < 2; mt++) {
            const int ro = (wi * 32 + mt * 16 + m) * 32 + ((kq ^ rkey) * 8);
            ah[mt] = *(const short8*)&Ah[buf][ro];
            al[mt] = *(const short8*)&Al[buf][ro];
        }
#pragma unroll
        for (int nt = 0; nt < 2; nt++) {
            const int ro = (wj * 32 + nt * 16 + m) * 32 + ((kq ^ rkey) * 8);
            bh[nt] = *(const short8*)&Bh[buf][ro];
            bl[nt] = *(const short8*)&Bl[buf][ro];
        }
#pragma unroll
        for (int mt = 0; mt < 2; mt++)
#pragma unroll
            for (int nt = 0; nt < 2; nt++) {
                acc[mt][nt] = __builtin_amdgcn_mfma_f32_16x16x32_bf16(
                    ah[mt], bh[nt], acc[mt][nt], 0, 0, 0);
                acc[mt][nt] = __builtin_amdgcn_mfma_f32_16x16x32_bf16(
                    ah[mt], bl[nt], acc[mt][nt], 0, 0, 0);
                acc[mt][nt] = __builtin_amdgcn_mfma_f32_16x16x32_bf16(
                    al[mt], bh[nt], acc[mt][nt], 0, 0, 0);
            }
        if (kt < 7) {                       // deposit prefetch into other buf
            const int nb = buf ^ 1;
            *(uint4*)&Ah[nb][woff] = a0n;
            *(uint4*)&Al[nb][woff] = a1n;
            *(uint4*)&Bh[nb][woff] = w0n;
            *(uint4*)&Bl[nb][woff] = w1n;
        }
        __syncthreads();
    }
    float bv[2];
#pragma unroll
    for (int nt = 0; nt < 2; nt++) bv[nt] = bias[j0 + wj * 32 + nt * 16 + m];
#pragma unroll
    for (int mt = 0; mt < 2; mt++)
#pragma unroll
        for (int nt = 0; nt < 2; nt++)
#pragma unroll
            for (int reg = 0; reg < 4; reg++) {
                const int row = i0 + wi * 32 + mt * 16 + kq * 4 + reg;
                if (row < N_NODES)
                    sup[(size_t)row * 128 + j0 + wj * 32 + nt * 16 + m] =
                        acc[mt][nt][reg] + bv[nt];
            }
}

// ------- reorder both halves: packed (src, val) -----------------------------
__global__ __launch_bounds__(256) void k_reorder2(const int* __restrict__ s0,
                                                  const int* __restrict__ d0,
                                                  const float* __restrict__ v0,
                                                  const int* __restrict__ s1,
                                                  const int* __restrict__ d1,
                                                  const float* __restrict__ v1,
                                                  int* __restrict__ cur,
                                                  int2* __restrict__ packed) {
    int b = blockIdx.x;
    const int *src, *dst;
    const float* val;
    int* c;
    int2* pk;
    if (b < 1250) { src = s0; dst = d0; val = v0; c = cur; pk = packed; }
    else { b -= 1250; src = s1; dst = d1; val = v1; c = cur + 10240; pk = packed + E_EDGES; }
    const int e = b * 256 + threadIdx.x;
    const int d = dst[e];
    const int p = atomicAdd(&c[d], 1);
    pk[p] = make_int2(src[e], __float_as_int(val[e]));
}

// ------- CSR aggregate + per-half normalize + fused xbf write ---------------
__global__ __launch_bounds__(256) void k_agg2(const float* __restrict__ sup0,
                                              const float* __restrict__ sup1,
                                              const int* __restrict__ off_,
                                              const int* __restrict__ hist_,
                                              const int2* __restrict__ packed_,
                                              float* __restrict__ xall,
                                              unsigned short* __restrict__ xbf) {
    const int b = blockIdx.x;
    const int t = threadIdx.x, wave = t >> 6, lane = t & 63;
    if (b >= AGG_MAIN) {                    // zero xbf pad rows
        const int idx = (b - AGG_MAIN) * 256 + t;
        ((uint2*)(xbf + (size_t)N_NODES * 256))[idx] = make_uint2(0u, 0u);
        return;
    }
    const int node = b * 2 + (wave >> 1);
    const int half = wave & 1;
    const int l = lane & 31, side = lane >> 5;
    const float4* S4 = (const float4*)(half ? sup1 : sup0);
    const int* off = off_ + half * 10240;
    const int* hist = hist_ + half * 10240;
    const int2* pk = packed_ + (size_t)half * E_EDGES;
    const int s0 = off[node], cnt = hist[node], end = s0 + cnt;
    float4 acc = {0.f, 0.f, 0.f, 0.f};
    float4 acc2 = {0.f, 0.f, 0.f, 0.f};
    int e = s0;
    for (; e + 7 < end; e += 8) {           // 8 edges in flight (4 per side)
        const int2 p0 = pk[e + side];
        const int2 p1 = pk[e + 2 + side];
        const int2 p2 = pk[e + 4 + side];
        const int2 p3 = pk[e + 6 + side];
        const float v0 = __int_as_float(p0.y), v1 = __int_as_float(p1.y);
        const float v2 = __int_as_float(p2.y), v3 = __int_as_float(p3.y);
        const float4 m0 = S4[(size_t)p0.x * 32 + l];
        const float4 m1 = S4[(size_t)p1.x * 32 + l];
        const float4 m2 = S4[(size_t)p2.x * 32 + l];
        const float4 m3 = S4[(size_t)p3.x * 32 + l];
        acc.x  = fmaf(m0.x, v0, acc.x);  acc.y  = fmaf(m0.y, v0, acc.y);
        acc.z  = fmaf(m0.z, v0, acc.z);  acc.w  = fmaf(m0.w, v0, acc.w);
        acc2.x = fmaf(m1.x, v1, acc2.x); acc2.y = fmaf(m1.y, v1, acc2.y);
        acc2.z = fmaf(m1.z, v1, acc2.z); acc2.w = fmaf(m1.w, v1, acc2.w);
        acc.x  = fmaf(m2.x, v2, acc.x);  acc.y  = fmaf(m2.y, v2, acc.y);
        acc.z  = fmaf(m2.z, v2, acc.z);  acc.w  = fmaf(m2.w, v2, acc.w);
        acc2.x = fmaf(m3.x, v3, acc2.x); acc2.y = fmaf(m3.y, v3, acc2.y);
        acc2.z = fmaf(m3.z, v3, acc2.z); acc2.w = fmaf(m3.w, v3, acc2.w);
    }
    for (; e + 3 < end; e += 4) {
        const int2 p0 = pk[e + side];
        const int2 p1 = pk[e + 2 + side];
        const float v0 = __int_as_float(p0.y), v1 = __int_as_float(p1.y);
        const float4 m0 = S4[(size_t)p0.x * 32 + l];
        const float4 m1 = S4[(size_t)p1.x * 32 + l];
        acc.x  = fmaf(m0.x, v0, acc.x);  acc.y  = fmaf(m0.y, v0, acc.y);
        acc.z  = fmaf(m0.z, v0, acc.z);  acc.w  = fmaf(m0.w, v0, acc.w);
        acc2.x = fmaf(m1.x, v1, acc2.x); acc2.y = fmaf(m1.y, v1, acc2.y);
        acc2.z = fmaf(m1.z, v1, acc2.z); acc2.w = fmaf(m1.w, v1, acc2.w);
    }
    for (; e < end; e += 2) {
        const int ee = e + side;
        if (ee < end) {
            const int2 p = pk[ee];
            const float v = __int_as_float(p.y);
            const float4 m = S4[(size_t)p.x * 32 + l];
            acc.x = fmaf(m.x, v, acc.x); acc.y = fmaf(m.y, v, acc.y);
            acc.z = fmaf(m.z, v, acc.z); acc.w = fmaf(m.w, v, acc.w);
        }
    }
    acc.x += acc2.x; acc.y += acc2.y; acc.z += acc2.z; acc.w += acc2.w;
    // combine the two half-wave partial sums (feature f = 4l+c)
    float4 full;
    full.x = acc.x + __shfl_xor(acc.x, 32, 64);
    full.y = acc.y + __shfl_xor(acc.y, 32, 64);
    full.z = acc.z + __shfl_xor(acc.z, 32, 64);
    full.w = acc.w + __shfl_xor(acc.w, 32, 64);
    float ssum = full.x * full.x + full.y * full.y + full.z * full.z + full.w * full.w;
#pragma unroll
    for (int o = 16; o > 0; o >>= 1) ssum += __shfl_xor(ssum, o, 64);
    const float inv = 1.0f / sqrtf(ssum);
    if (side == 0) {
        float4 ov;
        ov.x = full.x * inv; ov.y = full.y * inv;
        ov.z = full.z * inv; ov.w = full.w * inv;
        ((float4*)xall)[(size_t)node * 64 + half * 32 + l] = ov;
        const float s2 = 0.70710678118654752440f;   // 1/sqrt(2) == rn
        uint2 pv;
        pv.x = (unsigned)f2bf(ov.x * s2) | ((unsigned)f2bf(ov.y * s2) << 16);
        pv.y = (unsigned)f2bf(ov.z * s2) | ((unsigned)f2bf(ov.w * s2) << 16);
        ((uint2*)(xbf + (size_t)node * 256 + half * 128))[l] = pv;
    }
}

// ======= filter (512 thr): reg-staged dbuf MFMA over upper-tri 128-tiles ====
// 8 waves/block, wave (wi=wave&1, wj=wave>>1) owns 64x32 quadrant.
__global__ __launch_bounds__(512) void k_filter(const unsigned short* __restrict__ xbf,
                                                int* __restrict__ count,
                                                int* __restrict__ list) {
    __shared__ unsigned short As[2][128 * 32];
    __shared__ unsigned short Bs[2][128 * 32];
    __shared__ int hf[8];
    const int u = blockIdx.x;
    const int t = threadIdx.x, wave = t >> 6, lane = t & 63;
    const int m = lane & 15, kq = lane >> 4;
    int i = (int)((2.0 * TILES2 + 1.0 -
                   sqrt((2.0 * TILES2 + 1.0) * (2.0 * TILES2 + 1.0) - 8.0 * (double)u)) * 0.5);
    if (i < 0) i = 0;
    while ((i + 1) * TILES2 - ((i + 1) * i) / 2 <= u) i++;
    while (i * TILES2 - (i * (i - 1)) / 2 > u) i--;
    const int ti = i;
    const int tj = i + (u - (i * TILES2 - (i * (i - 1)) / 2));

    const int wi = wave & 1, wj = wave >> 1;   // 64-row half, 32-col quarter
    const int i0 = ti * 128, j0 = tj * 128;
    const int srow = lane >> 2, scol = lane & 3;
    const int skey = (srow >> 1) & 3;
    const int rkey = (m >> 1) & 3;
    if (t < 8) hf[t] = 0;

    // staging pointers (reg path); wave stages its 16-row group of A and B
    const unsigned short* pA = xbf + (size_t)(i0 + wave * 16 + srow) * 256 + (scol ^ skey) * 8;
    const unsigned short* pB = xbf + (size_t)(j0 + wave * 16 + srow) * 256 + (scol ^ skey) * 8;
    const int woff = wave * 512 + srow * 32 + scol * 8;

    f32x4 acc[4][2];
#pragma unroll
    for (int r = 0; r < 4; r++)
#pragma unroll
        for (int c = 0; c < 2; c++) acc[r][c] = (f32x4){0.f, 0.f, 0.f, 0.f};

    {   // stage kt=0 via regs
        uint4 ra = *(const uint4*)pA;
        uint4 rb = *(const uint4*)pB;
        *(uint4*)&As[0][woff] = ra;
        *(uint4*)&Bs[0][woff] = rb;
    }
    __syncthreads();

#pragma unroll
    for (int kt = 0; kt < 8; kt++) {
        const int buf = kt & 1;
        uint4 ran, rbn;
        if (kt < 7) {                       // prefetch kt+1 into regs
            ran = *(const uint4*)(pA + (kt + 1) * 32);
            rbn = *(const uint4*)(pB + (kt + 1) * 32);
        }
        short8 af[4], bfr[2];
#pragma unroll
        for (int mt = 0; mt < 4; mt++)
            af[mt] = *(const short8*)&As[buf][(wi * 64 + mt * 16 + m) * 32 + ((kq ^ rkey) * 8)];
#pragma unroll
        for (int nt = 0; nt < 2; nt++)
            bfr[nt] = *(const short8*)&Bs[buf][(wj * 32 + nt * 16 + m) * 32 + ((kq ^ rkey) * 8)];
#pragma unroll
        for (int mt = 0; mt < 4; mt++)
#pragma unroll
            for (int nt = 0; nt < 2; nt++)
                acc[mt][nt] = __builtin_amdgcn_mfma_f32_16x16x32_bf16(
                    af[mt], bfr[nt], acc[mt][nt], 0, 0, 0);
        if (kt < 7) {                       // deposit prefetch into other buf
            const int nb = buf ^ 1;
            *(uint4*)&As[nb][woff] = ran;
            *(uint4*)&Bs[nb][woff] = rbn;
        }
        __syncthreads();
    }

    bool hit = false;
    const int rbase = i0 + wi * 64 + kq * 4;
    const int cbase = j0 + wj * 32 + m;
#pragma unroll
    for (int mt = 0; mt < 4; mt++)
#pragma unroll
        for (int nt = 0; nt < 2; nt++) {
            const f32x4 a = acc[mt][nt];
#pragma unroll
            for (int reg = 0; reg < 4; reg++) {
                if (a[reg] > 0.94f) {
                    const int ii = rbase + mt * 16 + reg;
                    const int jj = cbase + nt * 16;
                    if (jj > ii && ii < N_NODES && jj < N_NODES) hit = true;
                }
            }
        }
    if (__ballot(hit) != 0ull && lane == 0) hf[wave] = 1;
    __syncthreads();
    if (t == 0) {                           // dedupe: 4 64x64 quadrants
#pragma unroll
        for (int q = 0; q < 4; q++) {
            const int qwi = q >> 1, qcj = q & 1;
            if (hf[qwi + 4 * qcj] | hf[qwi + 4 * qcj + 2]) {
                const int slot = atomicAdd(count, 1);
                list[slot] = ((ti * 2 + qwi) << 16) | (tj * 2 + qcj);
            }
        }
    }
}

// ======= pair losses (512 thr): MFMA diag dot products ======================
__global__ __launch_bounds__(512) void k_pairs(const unsigned short* __restrict__ xbf,
                                               const int* __restrict__ train,
                                               const int* __restrict__ negidx,
                                               const int* __restrict__ na,
                                               const int* __restrict__ nb,
                                               const int* __restrict__ nl,
                                               const int* __restrict__ neg_row,
                                               float* __restrict__ neg_s,
                                               float* __restrict__ preal,
                                               float* __restrict__ plc) {
    __shared__ float wsum[8];
    const int b = blockIdx.x;
    const int t = threadIdx.x, wave = t >> 6, lane = t & 63;
    const int m = lane & 15, kq = lane >> 4;
    const int dreg = ((m >> 2) == kq) ? (m & 3) : -1;   // diag ownership

    if (b < RB) {   // ================= loss_real =================
        const int g = b * 8 + wave;
        float sum = 0.f;
        if (g < 6250) {
            const int p = g * 16 + m;
            const int2 se = ((const int2*)train)[p];
            const int ng = negidx[p];
            const unsigned short* pa = xbf + (size_t)se.x * 256 + kq * 8;
            const unsigned short* pb = xbf + (size_t)se.y * 256 + kq * 8;
            const unsigned short* pc = xbf + (size_t)ng * 256 + kq * 8;
            f32x4 P = {0.f, 0.f, 0.f, 0.f}, Q = P;
#pragma unroll
            for (int kt = 0; kt < 8; kt++) {
                const short8 a  = *(const short8*)(pa + kt * 32);
                const short8 bb = *(const short8*)(pb + kt * 32);
                const short8 cc = *(const short8*)(pc + kt * 32);
                P = __builtin_amdgcn_mfma_f32_16x16x32_bf16(a, bb, P, 0, 0, 0);
                Q = __builtin_amdgcn_mfma_f32_16x16x32_bf16(a, cc, Q, 0, 0, 0);
            }
            if (dreg >= 0) {
                const float pos = P[dreg], neg = Q[dreg];
                const float d0 = (pos - 0.1f) * (1.0f / 0.9f);
                sum = d0 * d0 * log1pf(expf(neg - pos));
            }
        }
        sum = wred64(sum);
        if (lane == 0) wsum[wave] = sum;
        __syncthreads();
        if (t == 0) {
            float s = 0.f;
#pragma unroll
            for (int w = 0; w < 8; w++) s += wsum[w];
            preal[b] = s;
        }
    } else if (b < RB + LB) {   // ================= lc =================
        const int bi = b - RB;
        const int g = bi * 8 + wave;
        float sum = 0.f;
        if (g < 938) {
            const int p = g * 16 + m;
            const bool valid = p < P_PAIRS;
            const int pc_ = valid ? p : (P_PAIRS - 1);
            const int a_ = na[pc_], b_ = nb[pc_];
            const unsigned short* pa = xbf + (size_t)a_ * 256 + kq * 8;
            const unsigned short* pb = xbf + (size_t)b_ * 256 + kq * 8;
            f32x4 P = {0.f, 0.f, 0.f, 0.f};
#pragma unroll
            for (int kt = 0; kt < 8; kt++) {
                const short8 a  = *(const short8*)(pa + kt * 32);
                const short8 bb = *(const short8*)(pb + kt * 32);
                P = __builtin_amdgcn_mfma_f32_16x16x32_bf16(a, bb, P, 0, 0, 0);
            }
            if (dreg >= 0 && valid) {
                const float sim = P[dreg];
                const float z = sim * 2.0f;                 // sim / TAU0
                const float logsig = -log1pf(expf(-z));
                const float gw = ldexpf(1.0f, -(nl[pc_] + 1));
                sum = gw * logsig;
            }
        }
        sum = wred64(sum);
        if (lane == 0) wsum[wave] = sum;
        __syncthreads();
        if (t == 0) {
            float s = 0.f;
#pragma unroll
            for (int w = 0; w < 8; w++) s += wsum[w];
            plc[bi] = s;
        }
    } else {   // ================= neg_s =================
        const int bi = b - RB - LB;
        const int g = bi * 8 + wave;
        if (g < 625) {
            const int node = g * 16 + m;
            const int j = neg_row[node];
            const unsigned short* pa = xbf + (size_t)node * 256 + kq * 8;
            const unsigned short* pb = xbf + (size_t)j * 256 + kq * 8;
            f32x4 P = {0.f, 0.f, 0.f, 0.f};
#pragma unroll
            for (int kt = 0; kt < 8; kt++) {
                const short8 a  = *(const short8*)(pa + kt * 32);
                const short8 bb = *(const short8*)(pb + kt * 32);
                P = __builtin_amdgcn_mfma_f32_16x16x32_bf16(a, bb, P, 0, 0, 0);
            }
            if (dreg >= 0) neg_s[node] = P[dreg];
        }
    }
}

// ------- phase B: exact fp32 recompute of flagged tiles + fused final -------
__global__ __launch_bounds__(256) void k_exact(const float* __restrict__ xall,
                                               const float* __restrict__ neg_s,
                                               const int* __restrict__ count,
                                               const int* __restrict__ list,
                                               float* __restrict__ pexact,
                                               const float* __restrict__ preal,
                                               const float* __restrict__ plc,
                                               int* __restrict__ donecnt,
                                               float* __restrict__ out_loss) {
    __shared__ float As[64 * 36];
    __shared__ float Bs[64 * 36];
    __shared__ float wsum[4];
    __shared__ int amlast;
    const int t = threadIdx.x;
    const int tx = t & 15, ty = t >> 4;
    const int li = t >> 2, kg = t & 3;
    const float4* X4 = (const float4*)xall;
    const int cnt = *count;
    float total = 0.0f;

    for (int idx = blockIdx.x; idx < cnt; idx += EXACT_BLOCKS) {
        const int pk = list[idx];
        const int ti = pk >> 16, tj = pk & 0xffff;
        const int i0 = ti * 64, j0 = tj * 64;
        float acc[4][4] = {};
        for (int kt = 0; kt < 8; kt++) {
            {
                const int gi = i0 + li;
                float4 v0 = {0, 0, 0, 0}, v1 = {0, 0, 0, 0};
                if (gi < N_NODES) {
                    v0 = X4[gi * 64 + kt * 8 + kg * 2];
                    v1 = X4[gi * 64 + kt * 8 + kg * 2 + 1];
                }
                *(float4*)&As[li * 36 + kg * 8]     = v0;
                *(float4*)&As[li * 36 + kg * 8 + 4] = v1;
                const int gj = j0 + li;
                float4 w0 = {0, 0, 0, 0}, w1 = {0, 0, 0, 0};
                if (gj < N_NODES) {
                    w0 = X4[gj * 64 + kt * 8 + kg * 2];
                    w1 = X4[gj * 64 + kt * 8 + kg * 2 + 1];
                }
                *(float4*)&Bs[li * 36 + kg * 8]     = w0;
                *(float4*)&Bs[li * 36 + kg * 8 + 4] = w1;
            }
            __syncthreads();
#pragma unroll
            for (int k = 0; k < 32; k += 2) {
                float2 av[4], bv[4];
#pragma unroll
                for (int r = 0; r < 4; r++) {
                    av[r] = *(const float2*)&As[(ty * 4 + r) * 36 + k];
                    bv[r] = *(const float2*)&Bs[(tx * 4 + r) * 36 + k];
                }
#pragma unroll
                for (int r = 0; r < 4; r++)
#pragma unroll
                    for (int c = 0; c < 4; c++)
                        acc[r][c] += av[r].x * bv[c].x + av[r].y * bv[c].y;
            }
            __syncthreads();
        }
#pragma unroll
        for (int r = 0; r < 4; r++) {
            const int i = i0 + ty * 4 + r;
            if (i >= N_NODES) continue;
            const float nsi = neg_s[i];
#pragma unroll
            for (int c = 0; c < 4; c++) {
                const int j = j0 + tx * 4 + c;
                if (j < N_NODES && j > i) {
                    const float s = acc[r][c] * 0.5f;   // rn_i*rn_j == 1/2
                    if (s > 0.95f) {
                        const float d0 = (s - 0.1f) * (1.0f / 0.9f);
                        total += d0 * d0 * log1pf(expf(nsi - s));
                    }
                }
            }
        }
    }
    float red = wred64(total);
    if ((t & 63) == 0) wsum[t >> 6] = red;
    __syncthreads();
    if (t == 0) {
        pexact[blockIdx.x] = wsum[0] + wsum[1] + wsum[2] + wsum[3];
        __threadfence();
        amlast = (atomicAdd(donecnt, 1) == EXACT_BLOCKS - 1);
    }
    __syncthreads();
    if (amlast) {                           // last block: final reduction
        __threadfence();
        float sr = 0.0f, sp = 0.0f, sl = 0.0f;
        for (int i = t; i < RB; i += 256) sr += preal[i];
        if (t < EXACT_BLOCKS) sp = pexact[t];
        if (t < LB) sl = plc[t];
        float contrib = sr + sp - sl * (1.0f / (float)P_PAIRS);
        contrib = wred64(contrib);
        if ((t & 63) == 0) wsum[t >> 6] = contrib;
        __syncthreads();
        if (t == 0) out_loss[0] = wsum[0] + wsum[1] + wsum[2] + wsum[3];
    }
}

extern "C" void kernel_launch(void* const* d_in, const int* in_sizes, int n_in,
                              void* d_out, int out_size, void* d_ws, size_t ws_size,
                              hipStream_t stream) {
    const float* x0   = (const float*)d_in[0];
    const float* x1   = (const float*)d_in[1];
    const int*   a0s  = (const int*)d_in[2];
    const int*   a0d  = (const int*)d_in[3];
    const float* a0v  = (const float*)d_in[4];
    const int*   a1s  = (const int*)d_in[5];
    const int*   a1d  = (const int*)d_in[6];
    const float* a1v  = (const float*)d_in[7];
    const int*   trn  = (const int*)d_in[8];
    const int*   ngi  = (const int*)d_in[9];
    const int*   ngr  = (const int*)d_in[10];
    const int*   na   = (const int*)d_in[11];
    const int*   nb   = (const int*)d_in[12];
    const int*   nl   = (const int*)d_in[13];
    const float* W0   = (const float*)d_in[14];
    const float* b0   = (const float*)d_in[15];
    const float* W1   = (const float*)d_in[16];
    const float* b1   = (const float*)d_in[17];

    float* xall = (float*)d_out;                 // N x 256
    float* loss = xall + (size_t)N_NODES * 256;  // scalar

    float* ws = (float*)d_ws;
    size_t o = 0;
    float* sup0 = ws;                o += 1280000;
    float* sup1 = ws + o;            o += 1280000;
    unsigned short* xbf = (unsigned short*)(ws + o); o += 1294336;  // NPAD2x256 bf16
    unsigned short* xh  = (unsigned short*)(ws + o); o += 2588672;  // 2 halves
    unsigned short* xl  = (unsigned short*)(ws + o); o += 2588672;
    unsigned short* wth = (unsigned short*)(ws + o); o += 32768;
    unsigned short* wtl = (unsigned short*)(ws + o); o += 32768;
    int2*  packed= (int2*)(ws + o);  o += 1280000;    // 2 x E int2
    int*   hist  = (int*)(ws + o);   o += 20480;      // both halves
    int*   count = (int*)(ws + o);   o += 16;         // [0]=filter cnt, [1]=done
    int*   off   = (int*)(ws + o);   o += 20480;
    int*   cur   = (int*)(ws + o);   o += 20480;
    float* negs  = ws + o;           o += 10000;
    float* preal = ws + o;           o += RB;
    float* plc   = ws + o;           o += LB;
    float* pexact= ws + o;           o += EXACT_BLOCKS;
    int*   list  = (int*)(ws + o);   o += NTRI2 * 4 + 16;

    hipMemsetAsync(hist, 0, 20496 * sizeof(int), stream);   // hist both + counters
    k_prep<<<7812, 256, 0, stream>>>(x0, x1, W0, W1, a0d, a1d,
                                     xh, xl, wth, wtl, hist);
    k_gemmscan<<<634, 256, 0, stream>>>(xh, xl, wth, wtl, b0, b1,
                                        sup0, sup1, hist, off, cur);
    k_reorder2<<<2500, 256, 0, stream>>>(a0s, a0d, a0v, a1s, a1d, a1v, cur, packed);
    k_agg2<<<AGG_MAIN + AGG_PAD, 256, 0, stream>>>(sup0, sup1, off, hist, packed,
                                                   xall, xbf);
    k_filter<<<NTRI2, 512, 0, stream>>>(xbf, count, list);
    k_pairs<<<RB + LB + NB, 512, 0, stream>>>(xbf, trn, ngi, na, nb, nl, ngr,
                                              negs, preal, plc);
    k_exact<<<EXACT_BLOCKS, 256, 0, stream>>>(xall, negs, count, list, pexact,
                                              preal, plc, count + 1, loss);
}

// Round 11
// 283.555 us; speedup vs baseline: 1.0635x; 1.0635x over previous
//
#include <hip/hip_runtime.h>
#include <math.h>

#define N_NODES 10000
#define E_EDGES 320000
#define M_TRAIN 100000
#define P_PAIRS 15000
#define TILES2  79            // 128-tile count: ceil(10000/128)
#define NTRI2   3160          // TILES2*(TILES2+1)/2
#define NPAD2   10112         // 79*128 padded rows
#define EXACT_BLOCKS 256
#define RB 782                // real-loss blocks (6250 groups / 8 waves)
#define LB 118                // lc blocks (938 groups / 8 waves)
#define NB 79                 // negs blocks (625 groups / 8 waves)
#define AGG_MAIN 5000
#define AGG_PAD  14           // zero 112 pad rows of xbf (3584 uint2 / 256)

typedef __attribute__((ext_vector_type(8))) short short8;   // 8 bf16 (4 VGPRs)
typedef __attribute__((ext_vector_type(4))) float f32x4;

__device__ __forceinline__ float wred64(float v) {
#pragma unroll
    for (int o = 32; o > 0; o >>= 1) v += __shfl_xor(v, o, 64);
    return v;
}

__device__ __forceinline__ unsigned short f2bf(float f) {   // RNE float->bf16
    unsigned u = __float_as_uint(f);
    u += 0x7fffu + ((u >> 16) & 1u);
    return (unsigned short)(u >> 16);
}
__device__ __forceinline__ float bf2f(unsigned short h) {
    return __uint_as_float((unsigned)h << 16);
}
__device__ __forceinline__ float bflo(unsigned u) {         // low bf16 of packed
    return __uint_as_float(u << 16);
}
__device__ __forceinline__ float bfhi(unsigned u) {         // high bf16 of packed
    return __uint_as_float(u & 0xffff0000u);
}

// split 8 fp32 into packed bf16 hi + lo residual (two-way split)
__device__ __forceinline__ void split8(const float4 a, const float4 b,
                                       uint4& hi, uint4& lo) {
    const unsigned short h0 = f2bf(a.x), h1 = f2bf(a.y);
    const unsigned short h2 = f2bf(a.z), h3 = f2bf(a.w);
    const unsigned short h4 = f2bf(b.x), h5 = f2bf(b.y);
    const unsigned short h6 = f2bf(b.z), h7 = f2bf(b.w);
    hi = make_uint4((unsigned)h0 | ((unsigned)h1 << 16),
                    (unsigned)h2 | ((unsigned)h3 << 16),
                    (unsigned)h4 | ((unsigned)h5 << 16),
                    (unsigned)h6 | ((unsigned)h7 << 16));
    lo = make_uint4((unsigned)f2bf(a.x - bf2f(h0)) | ((unsigned)f2bf(a.y - bf2f(h1)) << 16),
                    (unsigned)f2bf(a.z - bf2f(h2)) | ((unsigned)f2bf(a.w - bf2f(h3)) << 16),
                    (unsigned)f2bf(b.x - bf2f(h4)) | ((unsigned)f2bf(b.y - bf2f(h5)) << 16),
                    (unsigned)f2bf(b.z - bf2f(h6)) | ((unsigned)f2bf(b.w - bf2f(h7)) << 16));
}

// ======= prep: W^T hi/lo (blocks 0..255) + edge histograms (256..2755) ======
__global__ __launch_bounds__(256) void k_prep(const float* __restrict__ W0,
                                              const float* __restrict__ W1,
                                              const int* __restrict__ d0,
                                              const int* __restrict__ d1,
                                              unsigned short* __restrict__ wth,
                                              unsigned short* __restrict__ wtl,
                                              int* __restrict__ hist) {
    int b = blockIdx.x;
    const int t = threadIdx.x;
    if (b < 256) {                          // ---- W^T hi/lo ----
        const int half = b >= 128;
        if (half) b -= 128;
        const float* W = half ? W1 : W0;
        unsigned short* th = wth + half * 32768;
        unsigned short* tl = wtl + half * 32768;
        const int idx = b * 256 + t;        // idx = k*128 + n
        const int k = idx >> 7, n = idx & 127;
        const float v = W[idx];
        const unsigned short h = f2bf(v);
        th[n * 256 + k] = h;
        tl[n * 256 + k] = f2bf(v - bf2f(h));
    } else {                                // ---- histogram ----
        b -= 256;
        const int* dst;
        int* h;
        if (b < 1250) { dst = d0; h = hist; }
        else { b -= 1250; dst = d1; h = hist + 10240; }
        atomicAdd(&h[dst[b * 256 + t]], 1);
    }
}

// ======= MFMA GEMM (fp32 x, in-kernel bf16 split), bf16 sup out + scan ======
__global__ __launch_bounds__(256) void k_gemmscan(const float* __restrict__ x0,
                                                  const float* __restrict__ x1,
                                                  const unsigned short* __restrict__ wth,
                                                  const unsigned short* __restrict__ wtl,
                                                  const float* __restrict__ b0,
                                                  const float* __restrict__ b1,
                                                  unsigned short* __restrict__ sup0,
                                                  unsigned short* __restrict__ sup1,
                                                  const int* __restrict__ hist_,
                                                  int* __restrict__ off_,
                                                  int* __restrict__ cur_) {
    __shared__ unsigned short Ah[2][64 * 32], Al[2][64 * 32];
    __shared__ unsigned short Bh[2][64 * 32], Bl[2][64 * 32];
    __shared__ int ss[256];
    const int b = blockIdx.x;
    const int t = threadIdx.x;
    if (b >= 632) {                         // ---- scan ----
        const int h = b - 632;
        const int* hist = hist_ + h * 10240;
        int* off = off_ + h * 10240;
        int* cur = cur_ + h * 10240;
        int loc[40];
        int sum = 0;
        const int base = t * 40;
#pragma unroll
        for (int i = 0; i < 40; i++) { loc[i] = hist[base + i]; sum += loc[i]; }
        ss[t] = sum;
        __syncthreads();
        for (int o = 1; o < 256; o <<= 1) {
            int v = (t >= o) ? ss[t - o] : 0;
            __syncthreads();
            ss[t] += v;
            __syncthreads();
        }
        int run = ss[t] - sum;
#pragma unroll
        for (int i = 0; i < 40; i++) {
            off[base + i] = run;
            cur[base + i] = run;
            run += loc[i];
        }
        return;
    }
    const int half = b >= 316;
    const int r_ = half ? b - 316 : b;
    const int rt = r_ >> 1, ct = r_ & 1;
    const float* xp = half ? x1 : x0;
    const unsigned short* bhp = wth + half * 32768;
    const unsigned short* blp = wtl + half * 32768;
    const float* bias = half ? b1 : b0;
    unsigned short* sup = half ? sup1 : sup0;
    const int i0 = rt * 64, j0 = ct * 64;
    const int wave = t >> 6, lane = t & 63;
    const int wi = wave >> 1, wj = wave & 1;
    const int m = lane & 15, kq = lane >> 4;
    const int srow = lane >> 2, scol = lane & 3;
    const int skey = (srow >> 1) & 3;       // staging XOR key
    const int rkey = (m >> 1) & 3;          // read XOR key

    const int arow = i0 + wave * 16 + srow;
    const float* pX = xp + (size_t)(arow < N_NODES ? arow : N_NODES - 1) * 256
                      + (scol ^ skey) * 8;
    const unsigned short* pBh = bhp + (size_t)(j0 + wave * 16 + srow) * 256 + (scol ^ skey) * 8;
    const unsigned short* pBl = blp + (size_t)(j0 + wave * 16 + srow) * 256 + (scol ^ skey) * 8;
    const int woff = wave * 512 + srow * 32 + scol * 8;

    f32x4 acc[2][2];
#pragma unroll
    for (int r = 0; r < 2; r++)
#pragma unroll
        for (int c = 0; c < 2; c++) acc[r][c] = (f32x4){0.f, 0.f, 0.f, 0.f};

    {   // stage kt=0 via regs (convert x on the fly)
        const float4 v0 = *(const float4*)pX;
        const float4 v1 = *(const float4*)(pX + 4);
        uint4 ahx, alx;
        split8(v0, v1, ahx, alx);
        uint4 w0 = *(const uint4*)pBh;
        uint4 w1 = *(const uint4*)pBl;
        *(uint4*)&Ah[0][woff] = ahx;
        *(uint4*)&Al[0][woff] = alx;
        *(uint4*)&Bh[0][woff] = w0;
        *(uint4*)&Bl[0][woff] = w1;
    }
    __syncthreads();

#pragma unroll
    for (int kt = 0; kt < 8; kt++) {
        const int buf = kt & 1;
        float4 xn0, xn1;
        uint4 w0n, w1n;
        if (kt < 7) {                       // prefetch kt+1 into regs
            xn0 = *(const float4*)(pX + (kt + 1) * 32);
            xn1 = *(const float4*)(pX + (kt + 1) * 32 + 4);
            w0n = *(const uint4*)(pBh + (kt + 1) * 32);
            w1n = *(const uint4*)(pBl + (kt + 1) * 32);
        }
        short8 ah[2], al[2], bh[2], bl[2];
#pragma unroll
        for (int mt = 0; mt < 2; mt++) {
            const int ro = (wi * 32 + mt * 16 + m) * 32 + ((kq ^ rkey) * 8);
            ah[mt] = *(const short8*)&Ah[buf][ro];
            al[mt] = *(const short8*)&Al[buf][ro];
        }
#pragma unroll
        for (int nt = 0; nt < 2; nt++) {
            const int ro = (wj * 32 + nt * 16 + m) * 32 + ((kq ^ rkey) * 8);
            bh[nt] = *(const short8*)&Bh[buf][ro];
            bl[nt] = *(const short8*)&Bl[buf][ro];
        }
#pragma unroll
        for (int mt = 0; mt < 2; mt++)
#pragma unroll
            for (int nt = 0; nt < 2; nt++) {
                acc[mt][nt] = __builtin_amdgcn_mfma_f32_16x16x32_bf16(
                    ah[mt], bh[nt], acc[mt][nt], 0, 0, 0);
                acc[mt][nt] = __builtin_amdgcn_mfma_f32_16x16x32_bf16(
                    ah[mt], bl[nt], acc[mt][nt], 0, 0, 0);
                acc[mt][nt] = __builtin_amdgcn_mfma_f32_16x16x32_bf16(
                    al[mt], bh[nt], acc[mt][nt], 0, 0, 0);
            }
        if (kt < 7) {                       // convert + deposit into other buf
            const int nb = buf ^ 1;
            uint4 ahx, alx;
            split8(xn0, xn1, ahx, alx);
            *(uint4*)&Ah[nb][woff] = ahx;
            *(uint4*)&Al[nb][woff] = alx;
            *(uint4*)&Bh[nb][woff] = w0n;
            *(uint4*)&Bl[nb][woff] = w1n;
        }
        __syncthreads();
    }
    float bv[2];
#pragma unroll
    for (int nt = 0; nt < 2; nt++) bv[nt] = bias[j0 + wj * 32 + nt * 16 + m];
#pragma unroll
    for (int mt = 0; mt < 2; mt++)
#pragma unroll
        for (int nt = 0; nt < 2; nt++)
#pragma unroll
            for (int reg = 0; reg < 4; reg++) {
                const int row = i0 + wi * 32 + mt * 16 + kq * 4 + reg;
                if (row < N_NODES)
                    sup[(size_t)row * 128 + j0 + wj * 32 + nt * 16 + m] =
                        f2bf(acc[mt][nt][reg] + bv[nt]);
            }
}

// ------- reorder both halves: packed (src, val) -----------------------------
__global__ __launch_bounds__(256) void k_reorder2(const int* __restrict__ s0,
                                                  const int* __restrict__ d0,
                                                  const float* __restrict__ v0,
                                                  const int* __restrict__ s1,
                                                  const int* __restrict__ d1,
                                                  const float* __restrict__ v1,
                                                  int* __restrict__ cur,
                                                  int2* __restrict__ packed) {
    int b = blockIdx.x;
    const int *src, *dst;
    const float* val;
    int* c;
    int2* pk;
    if (b < 1250) { src = s0; dst = d0; val = v0; c = cur; pk = packed; }
    else { b -= 1250; src = s1; dst = d1; val = v1; c = cur + 10240; pk = packed + E_EDGES; }
    const int e = b * 256 + threadIdx.x;
    const int d = dst[e];
    const int p = atomicAdd(&c[d], 1);
    pk[p] = make_int2(src[e], __float_as_int(val[e]));
}

// ------- CSR aggregate (bf16 sup) + per-half normalize + fused xbf write ----
__global__ __launch_bounds__(256) void k_agg2(const unsigned short* __restrict__ sup0,
                                              const unsigned short* __restrict__ sup1,
                                              const int* __restrict__ off_,
                                              const int* __restrict__ hist_,
                                              const int2* __restrict__ packed_,
                                              float* __restrict__ xall,
                                              unsigned short* __restrict__ xbf) {
    const int b = blockIdx.x;
    const int t = threadIdx.x, wave = t >> 6, lane = t & 63;
    if (b >= AGG_MAIN) {                    // zero xbf pad rows
        const int idx = (b - AGG_MAIN) * 256 + t;
        ((uint2*)(xbf + (size_t)N_NODES * 256))[idx] = make_uint2(0u, 0u);
        return;
    }
    const int node = b * 2 + (wave >> 1);
    const int half = wave & 1;
    const int l = lane & 31, side = lane >> 5;
    const uint2* S2 = (const uint2*)(half ? sup1 : sup0);  // row = 32 uint2
    const int* off = off_ + half * 10240;
    const int* hist = hist_ + half * 10240;
    const int2* pk = packed_ + (size_t)half * E_EDGES;
    const int s0 = off[node], cnt = hist[node], end = s0 + cnt;
    float4 acc = {0.f, 0.f, 0.f, 0.f};
    float4 acc2 = {0.f, 0.f, 0.f, 0.f};
    int e = s0;
    for (; e + 7 < end; e += 8) {           // 8 edges in flight (4 per side)
        const int2 p0 = pk[e + side];
        const int2 p1 = pk[e + 2 + side];
        const int2 p2 = pk[e + 4 + side];
        const int2 p3 = pk[e + 6 + side];
        const float v0 = __int_as_float(p0.y), v1 = __int_as_float(p1.y);
        const float v2 = __int_as_float(p2.y), v3 = __int_as_float(p3.y);
        const uint2 q0 = S2[(size_t)p0.x * 32 + l];
        const uint2 q1 = S2[(size_t)p1.x * 32 + l];
        const uint2 q2 = S2[(size_t)p2.x * 32 + l];
        const uint2 q3 = S2[(size_t)p3.x * 32 + l];
        acc.x  = fmaf(bflo(q0.x), v0, acc.x);  acc.y  = fmaf(bfhi(q0.x), v0, acc.y);
        acc.z  = fmaf(bflo(q0.y), v0, acc.z);  acc.w  = fmaf(bfhi(q0.y), v0, acc.w);
        acc2.x = fmaf(bflo(q1.x), v1, acc2.x); acc2.y = fmaf(bfhi(q1.x), v1, acc2.y);
        acc2.z = fmaf(bflo(q1.y), v1, acc2.z); acc2.w = fmaf(bfhi(q1.y), v1, acc2.w);
        acc.x  = fmaf(bflo(q2.x), v2, acc.x);  acc.y  = fmaf(bfhi(q2.x), v2, acc.y);
        acc.z  = fmaf(bflo(q2.y), v2, acc.z);  acc.w  = fmaf(bfhi(q2.y), v2, acc.w);
        acc2.x = fmaf(bflo(q3.x), v3, acc2.x); acc2.y = fmaf(bfhi(q3.x), v3, acc2.y);
        acc2.z = fmaf(bflo(q3.y), v3, acc2.z); acc2.w = fmaf(bfhi(q3.y), v3, acc2.w);
    }
    for (; e + 3 < end; e += 4) {
        const int2 p0 = pk[e + side];
        const int2 p1 = pk[e + 2 + side];
        const float v0 = __int_as_float(p0.y), v1 = __int_as_float(p1.y);
        const uint2 q0 = S2[(size_t)p0.x * 32 + l];
        const uint2 q1 = S2[(size_t)p1.x * 32 + l];
        acc.x  = fmaf(bflo(q0.x), v0, acc.x);  acc.y  = fmaf(bfhi(q0.x), v0, acc.y);
        acc.z  = fmaf(bflo(q0.y), v0, acc.z);  acc.w  = fmaf(bfhi(q0.y), v0, acc.w);
        acc2.x = fmaf(bflo(q1.x), v1, acc2.x); acc2.y = fmaf(bfhi(q1.x), v1, acc2.y);
        acc2.z = fmaf(bflo(q1.y), v1, acc2.z); acc2.w = fmaf(bfhi(q1.y), v1, acc2.w);
    }
    for (; e < end; e += 2) {
        const int ee = e + side;
        if (ee < end) {
            const int2 p = pk[ee];
            const float v = __int_as_float(p.y);
            const uint2 q = S2[(size_t)p.x * 32 + l];
            acc.x = fmaf(bflo(q.x), v, acc.x); acc.y = fmaf(bfhi(q.x), v, acc.y);
            acc.z = fmaf(bflo(q.y), v, acc.z); acc.w = fmaf(bfhi(q.y), v, acc.w);
        }
    }
    acc.x += acc2.x; acc.y += acc2.y; acc.z += acc2.z; acc.w += acc2.w;
    // combine the two half-wave partial sums (feature f = 4l+c)
    float4 full;
    full.x = acc.x + __shfl_xor(acc.x, 32, 64);
    full.y = acc.y + __shfl_xor(acc.y, 32, 64);
    full.z = acc.z + __shfl_xor(acc.z, 32, 64);
    full.w = acc.w + __shfl_xor(acc.w, 32, 64);
    float ssum = full.x * full.x + full.y * full.y + full.z * full.z + full.w * full.w;
#pragma unroll
    for (int o = 16; o > 0; o >>= 1) ssum += __shfl_xor(ssum, o, 64);
    const float inv = 1.0f / sqrtf(ssum);
    if (side == 0) {
        float4 ov;
        ov.x = full.x * inv; ov.y = full.y * inv;
        ov.z = full.z * inv; ov.w = full.w * inv;
        ((float4*)xall)[(size_t)node * 64 + half * 32 + l] = ov;
        const float s2 = 0.70710678118654752440f;   // 1/sqrt(2) == rn
        uint2 pv;
        pv.x = (unsigned)f2bf(ov.x * s2) | ((unsigned)f2bf(ov.y * s2) << 16);
        pv.y = (unsigned)f2bf(ov.z * s2) | ((unsigned)f2bf(ov.w * s2) << 16);
        ((uint2*)(xbf + (size_t)node * 256 + half * 128))[l] = pv;
    }
}

// ======= mega-kernel (512 thr): reg-staged filter + MFMA pair losses ========
__global__ __launch_bounds__(512) void k_fp(const unsigned short* __restrict__ xbf,
                                            int* __restrict__ count,
                                            int* __restrict__ list,
                                            const int* __restrict__ train,
                                            const int* __restrict__ negidx,
                                            const int* __restrict__ na,
                                            const int* __restrict__ nb,
                                            const int* __restrict__ nl,
                                            const int* __restrict__ neg_row,
                                            float* __restrict__ neg_s,
                                            float* __restrict__ preal,
                                            float* __restrict__ plc) {
    __shared__ unsigned short As[2][128 * 32];
    __shared__ unsigned short Bs[2][128 * 32];
    __shared__ float wsum[8];
    __shared__ int hf[8];
    const int b = blockIdx.x;
    const int t = threadIdx.x, wave = t >> 6, lane = t & 63;
    const int m = lane & 15, kq = lane >> 4;
    const int dreg = ((m >> 2) == kq) ? (m & 3) : -1;   // diag ownership

    if (b < NTRI2) {   // ================= filter =================
        const int u = b;
        int i = (int)((2.0 * TILES2 + 1.0 -
                       sqrt((2.0 * TILES2 + 1.0) * (2.0 * TILES2 + 1.0) - 8.0 * (double)u)) * 0.5);
        if (i < 0) i = 0;
        while ((i + 1) * TILES2 - ((i + 1) * i) / 2 <= u) i++;
        while (i * TILES2 - (i * (i - 1)) / 2 > u) i--;
        const int ti = i;
        const int tj = i + (u - (i * TILES2 - (i * (i - 1)) / 2));

        const int wi = wave & 1, wj = wave >> 1;   // 64-row half, 32-col quarter
        const int i0 = ti * 128, j0 = tj * 128;
        const int srow = lane >> 2, scol = lane & 3;
        const int skey = (srow >> 1) & 3;
        const int rkey = (m >> 1) & 3;
        if (t < 8) hf[t] = 0;

        const unsigned short* pA = xbf + (size_t)(i0 + wave * 16 + srow) * 256 + (scol ^ skey) * 8;
        const unsigned short* pB = xbf + (size_t)(j0 + wave * 16 + srow) * 256 + (scol ^ skey) * 8;
        const int woff = wave * 512 + srow * 32 + scol * 8;

        f32x4 acc[4][2];
#pragma unroll
        for (int r = 0; r < 4; r++)
#pragma unroll
            for (int c = 0; c < 2; c++) acc[r][c] = (f32x4){0.f, 0.f, 0.f, 0.f};

        {   // stage kt=0 via regs
            uint4 ra = *(const uint4*)pA;
            uint4 rb = *(const uint4*)pB;
            *(uint4*)&As[0][woff] = ra;
            *(uint4*)&Bs[0][woff] = rb;
        }
        __syncthreads();

#pragma unroll
        for (int kt = 0; kt < 8; kt++) {
            const int buf = kt & 1;
            uint4 ran, rbn;
            if (kt < 7) {                   // prefetch kt+1 into regs
                ran = *(const uint4*)(pA + (kt + 1) * 32);
                rbn = *(const uint4*)(pB + (kt + 1) * 32);
            }
            short8 af[4], bfr[2];
#pragma unroll
            for (int mt = 0; mt < 4; mt++)
                af[mt] = *(const short8*)&As[buf][(wi * 64 + mt * 16 + m) * 32 + ((kq ^ rkey) * 8)];
#pragma unroll
            for (int nt = 0; nt < 2; nt++)
                bfr[nt] = *(const short8*)&Bs[buf][(wj * 32 + nt * 16 + m) * 32 + ((kq ^ rkey) * 8)];
#pragma unroll
            for (int mt = 0; mt < 4; mt++)
#pragma unroll
                for (int nt = 0; nt < 2; nt++)
                    acc[mt][nt] = __builtin_amdgcn_mfma_f32_16x16x32_bf16(
                        af[mt], bfr[nt], acc[mt][nt], 0, 0, 0);
            if (kt < 7) {                   // deposit prefetch into other buf
                const int nbuf = buf ^ 1;
                *(uint4*)&As[nbuf][woff] = ran;
                *(uint4*)&Bs[nbuf][woff] = rbn;
            }
            __syncthreads();
        }

        bool hit = false;
        const int rbase = i0 + wi * 64 + kq * 4;
        const int cbase = j0 + wj * 32 + m;
#pragma unroll
        for (int mt = 0; mt < 4; mt++)
#pragma unroll
            for (int nt = 0; nt < 2; nt++) {
                const f32x4 a = acc[mt][nt];
#pragma unroll
                for (int reg = 0; reg < 4; reg++) {
                    if (a[reg] > 0.94f) {
                        const int ii = rbase + mt * 16 + reg;
                        const int jj = cbase + nt * 16;
                        if (jj > ii && ii < N_NODES && jj < N_NODES) hit = true;
                    }
                }
            }
        if (__ballot(hit) != 0ull && lane == 0) hf[wave] = 1;
        __syncthreads();
        if (t == 0) {                       // dedupe: 4 64x64 quadrants
#pragma unroll
            for (int q = 0; q < 4; q++) {
                const int qwi = q >> 1, qcj = q & 1;
                if (hf[qwi + 4 * qcj] | hf[qwi + 4 * qcj + 2]) {
                    const int slot = atomicAdd(count, 1);
                    list[slot] = ((ti * 2 + qwi) << 16) | (tj * 2 + qcj);
                }
            }
        }
        return;
    }

    const int ridx = b - NTRI2;
    if (ridx < RB) {   // ================= loss_real =================
        const int g = ridx * 8 + wave;
        float sum = 0.f;
        if (g < 6250) {
            const int p = g * 16 + m;
            const int2 se = ((const int2*)train)[p];
            const int ng = negidx[p];
            const unsigned short* pa = xbf + (size_t)se.x * 256 + kq * 8;
            const unsigned short* pb = xbf + (size_t)se.y * 256 + kq * 8;
            const unsigned short* pc = xbf + (size_t)ng * 256 + kq * 8;
            f32x4 P = {0.f, 0.f, 0.f, 0.f}, Q = P;
#pragma unroll
            for (int kt = 0; kt < 8; kt++) {
                const short8 a  = *(const short8*)(pa + kt * 32);
                const short8 bb = *(const short8*)(pb + kt * 32);
                const short8 cc = *(const short8*)(pc + kt * 32);
                P = __builtin_amdgcn_mfma_f32_16x16x32_bf16(a, bb, P, 0, 0, 0);
                Q = __builtin_amdgcn_mfma_f32_16x16x32_bf16(a, cc, Q, 0, 0, 0);
            }
            if (dreg >= 0) {
                const float pos = P[dreg], neg = Q[dreg];
                const float d0 = (pos - 0.1f) * (1.0f / 0.9f);
                sum = d0 * d0 * log1pf(expf(neg - pos));
            }
        }
        sum = wred64(sum);
        if (lane == 0) wsum[wave] = sum;
        __syncthreads();
        if (t == 0) {
            float s = 0.f;
#pragma unroll
            for (int w = 0; w < 8; w++) s += wsum[w];
            preal[ridx] = s;
        }
    } else if (ridx < RB + LB) {   // ================= lc =================
        const int bi = ridx - RB;
        const int g = bi * 8 + wave;
        float sum = 0.f;
        if (g < 938) {
            const int p = g * 16 + m;
            const bool valid = p < P_PAIRS;
            const int pc_ = valid ? p : (P_PAIRS - 1);
            const int a_ = na[pc_], b_ = nb[pc_];
            const unsigned short* pa = xbf + (size_t)a_ * 256 + kq * 8;
            const unsigned short* pb = xbf + (size_t)b_ * 256 + kq * 8;
            f32x4 P = {0.f, 0.f, 0.f, 0.f};
#pragma unroll
            for (int kt = 0; kt < 8; kt++) {
                const short8 a  = *(const short8*)(pa + kt * 32);
                const short8 bb = *(const short8*)(pb + kt * 32);
                P = __builtin_amdgcn_mfma_f32_16x16x32_bf16(a, bb, P, 0, 0, 0);
            }
            if (dreg >= 0 && valid) {
                const float sim = P[dreg];
                const float z = sim * 2.0f;                 // sim / TAU0
                const float logsig = -log1pf(expf(-z));
                const float gw = ldexpf(1.0f, -(nl[pc_] + 1));
                sum = gw * logsig;
            }
        }
        sum = wred64(sum);
        if (lane == 0) wsum[wave] = sum;
        __syncthreads();
        if (t == 0) {
            float s = 0.f;
#pragma unroll
            for (int w = 0; w < 8; w++) s += wsum[w];
            plc[bi] = s;
        }
    } else {   // ================= neg_s =================
        const int bi = ridx - RB - LB;
        const int g = bi * 8 + wave;
        if (g < 625) {
            const int node = g * 16 + m;
            const int j = neg_row[node];
            const unsigned short* pa = xbf + (size_t)node * 256 + kq * 8;
            const unsigned short* pb = xbf + (size_t)j * 256 + kq * 8;
            f32x4 P = {0.f, 0.f, 0.f, 0.f};
#pragma unroll
            for (int kt = 0; kt < 8; kt++) {
                const short8 a  = *(const short8*)(pa + kt * 32);
                const short8 bb = *(const short8*)(pb + kt * 32);
                P = __builtin_amdgcn_mfma_f32_16x16x32_bf16(a, bb, P, 0, 0, 0);
            }
            if (dreg >= 0) neg_s[node] = P[dreg];
        }
    }
}

// ------- phase B: exact fp32 recompute of flagged tiles + fused final -------
__global__ __launch_bounds__(256) void k_exact(const float* __restrict__ xall,
                                               const float* __restrict__ neg_s,
                                               const int* __restrict__ count,
                                               const int* __restrict__ list,
                                               float* __restrict__ pexact,
                                               const float* __restrict__ preal,
                                               const float* __restrict__ plc,
                                               int* __restrict__ donecnt,
                                               float* __restrict__ out_loss) {
    __shared__ float As[64 * 36];
    __shared__ float Bs[64 * 36];
    __shared__ float wsum[4];
    __shared__ int amlast;
    const int t = threadIdx.x;
    const int tx = t & 15, ty = t >> 4;
    const int li = t >> 2, kg = t & 3;
    const float4* X4 = (const float4*)xall;
    const int cnt = *count;
    float total = 0.0f;

    for (int idx = blockIdx.x; idx < cnt; idx += EXACT_BLOCKS) {
        const int pk = list[idx];
        const int ti = pk >> 16, tj = pk & 0xffff;
        const int i0 = ti * 64, j0 = tj * 64;
        float acc[4][4] = {};
        for (int kt = 0; kt < 8; kt++) {
            {
                const int gi = i0 + li;
                float4 v0 = {0, 0, 0, 0}, v1 = {0, 0, 0, 0};
                if (gi < N_NODES) {
                    v0 = X4[gi * 64 + kt * 8 + kg * 2];
                    v1 = X4[gi * 64 + kt * 8 + kg * 2 + 1];
                }
                *(float4*)&As[li * 36 + kg * 8]     = v0;
                *(float4*)&As[li * 36 + kg * 8 + 4] = v1;
                const int gj = j0 + li;
                float4 w0 = {0, 0, 0, 0}, w1 = {0, 0, 0, 0};
                if (gj < N_NODES) {
                    w0 = X4[gj * 64 + kt * 8 + kg * 2];
                    w1 = X4[gj * 64 + kt * 8 + kg * 2 + 1];
                }
                *(float4*)&Bs[li * 36 + kg * 8]     = w0;
                *(float4*)&Bs[li * 36 + kg * 8 + 4] = w1;
            }
            __syncthreads();
#pragma unroll
            for (int k = 0; k < 32; k += 2) {
                float2 av[4], bv[4];
#pragma unroll
                for (int r = 0; r < 4; r++) {
                    av[r] = *(const float2*)&As[(ty * 4 + r) * 36 + k];
                    bv[r] = *(const float2*)&Bs[(tx * 4 + r) * 36 + k];
                }
#pragma unroll
                for (int r = 0; r < 4; r++)
#pragma unroll
                    for (int c = 0; c < 4; c++)
                        acc[r][c] += av[r].x * bv[c].x + av[r].y * bv[c].y;
            }
            __syncthreads();
        }
#pragma unroll
        for (int r = 0; r < 4; r++) {
            const int i = i0 + ty * 4 + r;
            if (i >= N_NODES) continue;
            const float nsi = neg_s[i];
#pragma unroll
            for (int c = 0; c < 4; c++) {
                const int j = j0 + tx * 4 + c;
                if (j < N_NODES && j > i) {
                    const float s = acc[r][c] * 0.5f;   // rn_i*rn_j == 1/2
                    if (s > 0.95f) {
                        const float d0 = (s - 0.1f) * (1.0f / 0.9f);
                        total += d0 * d0 * log1pf(expf(nsi - s));
                    }
                }
            }
        }
    }
    float red = wred64(total);
    if ((t & 63) == 0) wsum[t >> 6] = red;
    __syncthreads();
    if (t == 0) {
        pexact[blockIdx.x] = wsum[0] + wsum[1] + wsum[2] + wsum[3];
        __threadfence();
        amlast = (atomicAdd(donecnt, 1) == EXACT_BLOCKS - 1);
    }
    __syncthreads();
    if (amlast) {                           // last block: final reduction
        __threadfence();
        float sr = 0.0f, sp = 0.0f, sl = 0.0f;
        for (int i = t; i < RB; i += 256) sr += preal[i];
        if (t < EXACT_BLOCKS) sp = pexact[t];
        if (t < LB) sl = plc[t];
        float contrib = sr + sp - sl * (1.0f / (float)P_PAIRS);
        contrib = wred64(contrib);
        if ((t & 63) == 0) wsum[t >> 6] = contrib;
        __syncthreads();
        if (t == 0) out_loss[0] = wsum[0] + wsum[1] + wsum[2] + wsum[3];
    }
}

extern "C" void kernel_launch(void* const* d_in, const int* in_sizes, int n_in,
                              void* d_out, int out_size, void* d_ws, size_t ws_size,
                              hipStream_t stream) {
    const float* x0   = (const float*)d_in[0];
    const float* x1   = (const float*)d_in[1];
    const int*   a0s  = (const int*)d_in[2];
    const int*   a0d  = (const int*)d_in[3];
    const float* a0v  = (const float*)d_in[4];
    const int*   a1s  = (const int*)d_in[5];
    const int*   a1d  = (const int*)d_in[6];
    const float* a1v  = (const float*)d_in[7];
    const int*   trn  = (const int*)d_in[8];
    const int*   ngi  = (const int*)d_in[9];
    const int*   ngr  = (const int*)d_in[10];
    const int*   na   = (const int*)d_in[11];
    const int*   nb   = (const int*)d_in[12];
    const int*   nl   = (const int*)d_in[13];
    const float* W0   = (const float*)d_in[14];
    const float* b0   = (const float*)d_in[15];
    const float* W1   = (const float*)d_in[16];
    const float* b1   = (const float*)d_in[17];

    float* xall = (float*)d_out;                 // N x 256
    float* loss = xall + (size_t)N_NODES * 256;  // scalar

    float* ws = (float*)d_ws;
    size_t o = 0;
    unsigned short* sup0 = (unsigned short*)ws;      o += 640000;   // 10000x128 bf16
    unsigned short* sup1 = (unsigned short*)(ws + o); o += 640000;
    unsigned short* xbf  = (unsigned short*)(ws + o); o += 1294336; // NPAD2x256 bf16
    unsigned short* wth  = (unsigned short*)(ws + o); o += 32768;   // 2 halves
    unsigned short* wtl  = (unsigned short*)(ws + o); o += 32768;
    int2*  packed = (int2*)(ws + o); o += 1280000;    // 2 x E int2
    int*   hist   = (int*)(ws + o);  o += 20480;      // both halves
    int*   count  = (int*)(ws + o);  o += 16;         // [0]=filter cnt, [1]=done
    int*   off    = (int*)(ws + o);  o += 20480;
    int*   cur    = (int*)(ws + o);  o += 20480;
    float* negs   = ws + o;          o += 10000;
    float* preal  = ws + o;          o += RB;
    float* plc    = ws + o;          o += LB;
    float* pexact = ws + o;          o += EXACT_BLOCKS;
    int*   list   = (int*)(ws + o);  o += NTRI2 * 4 + 16;

    hipMemsetAsync(hist, 0, 20496 * sizeof(int), stream);   // hist both + counters
    k_prep<<<2756, 256, 0, stream>>>(W0, W1, a0d, a1d, wth, wtl, hist);
    k_gemmscan<<<634, 256, 0, stream>>>(x0, x1, wth, wtl, b0, b1,
                                        sup0, sup1, hist, off, cur);
    k_reorder2<<<2500, 256, 0, stream>>>(a0s, a0d, a0v, a1s, a1d, a1v, cur, packed);
    k_agg2<<<AGG_MAIN + AGG_PAD, 256, 0, stream>>>(sup0, sup1, off, hist, packed,
                                                   xall, xbf);
    k_fp<<<NTRI2 + RB + LB + NB, 512, 0, stream>>>(xbf, count, list, trn, ngi,
                                                   na, nb, nl, ngr,
                                                   negs, preal, plc);
    k_exact<<<EXACT_BLOCKS, 256, 0, stream>>>(xall, negs, count, list, pexact,
                                              preal, plc, count + 1, loss);
}